// Round 7
// baseline (325.804 us; speedup 1.0000x reference)
//
#include <hip/hip_runtime.h>

typedef unsigned short u16;
typedef unsigned int   u32;

#define T_TOK 4096
#define D_DIM 1024
#define H_DIM 512
#define E_NUM 8
#define NP1   4608        // padded entries per pass (buckets padded to 64)
#define MAXP  4608
#define BIG_WS 43122688ull

typedef __bf16 bf16x8 __attribute__((ext_vector_type(8)));
typedef float  f32x4  __attribute__((ext_vector_type(4)));

// ---------- bf16 helpers ----------
__device__ __forceinline__ u16 f2bf(float f) {
    u32 x = __float_as_uint(f);
    x += 0x7fffu + ((x >> 16) & 1u);   // round-to-nearest-even
    return (u16)(x >> 16);
}
__device__ __forceinline__ u32 pk2(float a, float b) {
    return (u32)f2bf(a) | ((u32)f2bf(b) << 16);
}

#define LDF(arr, r, koff) __builtin_bit_cast(bf16x8, *(const uint4*)(&arr[r][koff]))
#define MFMA(a, b, c) __builtin_amdgcn_mfma_f32_16x16x32_bf16(a, b, c, 0, 0, 0)

// ---------- conv: w_in/w_out fp32 -> bf16 (memory-bound, once per launch) ----------
__global__ __launch_bounds__(256) void conv_kernel(
    const float* __restrict__ w_in, const float* __restrict__ w_out,
    u16* __restrict__ wib, u16* __restrict__ wob)
{
    const int t = blockIdx.x * 256 + threadIdx.x;   // 262144 threads
    for (int i = t; i < (8 << 20) / 8; i += 262144) {
        const float4 a = *(const float4*)(w_in + (size_t)i * 8);
        const float4 b = *(const float4*)(w_in + (size_t)i * 8 + 4);
        uint4 o;
        o.x = pk2(a.x, a.y); o.y = pk2(a.z, a.w);
        o.z = pk2(b.x, b.y); o.w = pk2(b.z, b.w);
        *(uint4*)(wib + (size_t)i * 8) = o;
    }
    for (int i = t; i < (4 << 20) / 8; i += 262144) {
        const float4 a = *(const float4*)(w_out + (size_t)i * 8);
        const float4 b = *(const float4*)(w_out + (size_t)i * 8 + 4);
        uint4 o;
        o.x = pk2(a.x, a.y); o.y = pk2(a.z, a.w);
        o.z = pk2(b.x, b.y); o.w = pk2(b.z, b.w);
        *(uint4*)(wob + (size_t)i * 8) = o;
    }
}

// ---------- router: logits + top-2 gates + (optional) bf16 x emit ----------
__global__ __launch_bounds__(256) void router_kernel(
    const float* __restrict__ x, const float* __restrict__ wr,
    float* __restrict__ logits_out, int* __restrict__ top_e, float* __restrict__ top_g,
    u16* __restrict__ xb)
{
    __shared__ float wrL[E_NUM][1024];
    const int tid = threadIdx.x;
    #pragma unroll
    for (int i = 0; i < 8; ++i) {
        const int idx = (i * 256 + tid) * 4;
        *(float4*)&wrL[0][idx] = *(const float4*)(wr + idx);
    }
    __syncthreads();

    const int lane = tid & 63;
    const int wv   = tid >> 6;
    const int t0   = blockIdx.x * 16 + wv * 4;

    for (int tt = 0; tt < 4; ++tt) {
        const int t = t0 + tt;
        const float* xr = x + ((size_t)t << 10);
        float4 xv[4];
        #pragma unroll
        for (int j = 0; j < 4; ++j)
            xv[j] = *(const float4*)(xr + j * 256 + lane * 4);

        if (xb) {   // emit bf16 x (uniform branch; all lanes)
            #pragma unroll
            for (int j = 0; j < 4; ++j) {
                uint2 p;
                p.x = pk2(xv[j].x, xv[j].y);
                p.y = pk2(xv[j].z, xv[j].w);
                *(uint2*)(xb + ((size_t)t << 10) + j * 256 + lane * 4) = p;
            }
        }

        float acc[E_NUM];
        #pragma unroll
        for (int e = 0; e < E_NUM; ++e) acc[e] = 0.f;
        #pragma unroll
        for (int j = 0; j < 4; ++j) {
            #pragma unroll
            for (int e = 0; e < E_NUM; ++e) {
                const float4 w4 = *(const float4*)&wrL[e][j * 256 + lane * 4];
                acc[e] += xv[j].x * w4.x + xv[j].y * w4.y + xv[j].z * w4.z + xv[j].w * w4.w;
            }
        }
        #pragma unroll
        for (int off = 32; off >= 1; off >>= 1) {
            #pragma unroll
            for (int e = 0; e < E_NUM; ++e)
                acc[e] += __shfl_xor(acc[e], off);
        }
        if (lane == 0) {
            #pragma unroll
            for (int e = 0; e < E_NUM; ++e)
                logits_out[t * E_NUM + e] = acc[e];
            int i0 = 0; float v0 = acc[0];
            #pragma unroll
            for (int e = 1; e < E_NUM; ++e) { if (acc[e] > v0) { v0 = acc[e]; i0 = e; } }
            int i1 = (i0 == 0) ? 1 : 0; float v1 = acc[i1];
            #pragma unroll
            for (int e = 0; e < E_NUM; ++e) { if (e != i0 && e != i1 && acc[e] > v1) { v1 = acc[e]; i1 = e; } }
            const float ed = __expf(v1 - v0);
            const float g0 = 1.f / (1.f + ed);
            top_e[2 * t]     = i0;  top_e[2 * t + 1] = i1;
            top_g[2 * t]     = g0;  top_g[2 * t + 1] = 1.f - g0;
        }
    }
}

// ---------- countscan (R6, proven) ----------
__global__ __launch_bounds__(256) void countscan_kernel(
    const int* __restrict__ top_e, int* __restrict__ ws_i,
    int* __restrict__ e0, int* __restrict__ e1)
{
    __shared__ int hist[16];
    const int tid = threadIdx.x;
    if (tid < 16) hist[tid] = 0;
    for (int i = tid; i < MAXP; i += 256) { e0[i] = -1; e1[i] = -1; }
    __syncthreads();
    for (int i = tid; i < 2 * T_TOK; i += 256) {
        const int e = top_e[i] & 7;
        atomicAdd(&hist[2 * e + (i & 1)], 1);
    }
    __syncthreads();
    if (tid == 0) {
        for (int k = 0; k < 2; ++k) {
            int s = 0, nt2 = 0;
            int* tab2 = ws_i + (k ? 896 : 768);
            for (int e = 0; e < E_NUM; ++e) {
                const int b = 2 * e + k;
                const int c = hist[b];
                ws_i[b]            = c;
                ws_i[64 + b]       = s;
                ws_i[128 + 16 * b] = s;
                const int pc = (c + 63) & ~63;
                for (int j = 0; j < pc / 64 && nt2 < 72; ++j)
                    tab2[nt2++] = (e << 16) | (s + j * 64);
                s += pc;
            }
            ws_i[100 + k] = nt2;
        }
        int nt1 = 0;
        for (int k = 0; k < 2; ++k) {
            const int n2 = ws_i[100 + k];
            const int* tab2 = ws_i + (k ? 896 : 768);
            for (int j = 0; j < n2 && nt1 < 144; ++j) {
                const int tl = tab2[j];
                ws_i[512 + nt1++] = (tl & 0xFFFF0000) | ((tl & 0xFFFF) + k * NP1);
            }
        }
        ws_i[99] = nt1;
    }
}

// ---------- scatter (R6, proven) ----------
__global__ __launch_bounds__(256) void scatter_kernel(
    const int* __restrict__ top_e, int* __restrict__ ws_i,
    int* __restrict__ e0, int* __restrict__ e1)
{
    const int idx = blockIdx.x * 256 + threadIdx.x;
    const int e   = top_e[idx] & 7;
    const int k   = idx & 1;
    const int b   = 2 * e + k;
    int pos = atomicAdd(&ws_i[128 + 16 * b], 1);
    if (pos >= MAXP) pos = MAXP - 1;
    (k ? e1 : e0)[pos] = idx;
}

// ================== bf16-staged MFMA path (primary) ==================

// g1b: act = swiglu(xb @ wib[e]^T); pure bf16 loads, no conversions in loop
__global__ __launch_bounds__(256) void g1_mfma_b(
    const u16* __restrict__ xb, const u16* __restrict__ wib,
    const int* __restrict__ ws_i, const int* __restrict__ e0,
    const int* __restrict__ e1, u16* __restrict__ act)
{
    const int nt = ws_i[99];
    if ((int)blockIdx.y >= nt) return;
    const int tile = ws_i[512 + blockIdx.y];
    const int e  = tile >> 16;
    const int rb = tile & 0xFFFF;
    const int nc = blockIdx.x;

    __shared__ u16 xs[64][72];
    __shared__ u16 wt[128][72];
    __shared__ int tokL[64];

    const int tid = threadIdx.x;
    if (tid < 64) {
        const int ent = (rb >= NP1) ? e1[rb - NP1 + tid] : e0[rb + tid];
        tokL[tid] = (ent < 0) ? 0 : (ent >> 1);
    }
    __syncthreads();

    const int wid = tid >> 6;
    const int ln  = tid & 63;
    const int qd  = ln >> 4;
    const int lm  = ln & 15;
    const int r8  = tid >> 3;            // staging row 0..31
    const int seg = tid & 7;             // 8-bf16 segment

    const int xt0 = tokL[r8];
    const int xt1 = tokL[32 + r8];
    int wrow[4];
    #pragma unroll
    for (int s = 0; s < 4; ++s) {
        const int row = s * 32 + r8;
        wrow[s] = (row < 64) ? (nc * 64 + row) : (448 + nc * 64 + row);
    }
    const u16* wbase = wib + ((size_t)e << 20);

    f32x4 accA[4], accB[4];
    #pragma unroll
    for (int i = 0; i < 4; ++i) { accA[i] = (f32x4){0.f,0.f,0.f,0.f}; accB[i] = (f32x4){0.f,0.f,0.f,0.f}; }

    for (int k0 = 0; k0 < 1024; k0 += 64) {
        uint4 xv0, xv1, wv[4];
        xv0 = *(const uint4*)(xb + ((size_t)xt0 << 10) + k0 + seg * 8);
        xv1 = *(const uint4*)(xb + ((size_t)xt1 << 10) + k0 + seg * 8);
        #pragma unroll
        for (int s = 0; s < 4; ++s)
            wv[s] = *(const uint4*)(wbase + ((size_t)wrow[s] << 10) + k0 + seg * 8);
        __syncthreads();
        *(uint4*)&xs[r8][seg * 8]      = xv0;
        *(uint4*)&xs[32 + r8][seg * 8] = xv1;
        #pragma unroll
        for (int s = 0; s < 4; ++s)
            *(uint4*)&wt[s * 32 + r8][seg * 8] = wv[s];
        __syncthreads();
        #pragma unroll
        for (int ki = 0; ki < 2; ++ki) {
            const int ko = ki * 32 + (qd << 3);
            const bf16x8 bA = LDF(wt, (wid << 4) + lm, ko);
            const bf16x8 bB = LDF(wt, 64 + (wid << 4) + lm, ko);
            #pragma unroll
            for (int i = 0; i < 4; ++i) {
                const bf16x8 aF = LDF(xs, (i << 4) + lm, ko);
                accA[i] = MFMA(aF, bA, accA[i]);
                accB[i] = MFMA(aF, bB, accB[i]);
            }
        }
    }

    #pragma unroll
    for (int i = 0; i < 4; ++i) {
        #pragma unroll
        for (int r = 0; r < 4; ++r) {
            const float a = accA[i][r], b = accB[i][r];
            const float v = b * a / (1.f + __expf(-a));
            const int row = (i << 4) + (qd << 2) + r;
            act[((size_t)(rb + row) << 9) + (nc << 6) + (wid << 4) + lm] = f2bf(v);
        }
    }
}

// g2b: out (+)= gate * (act @ wob[e]^T); pure bf16 loads
__global__ __launch_bounds__(256) void g2_mfma_b(
    const u16* __restrict__ act, const u16* __restrict__ wob,
    const int* __restrict__ ws_i, const int* __restrict__ entries,
    const float* __restrict__ top_g, float* __restrict__ out, int pass)
{
    const int nt = ws_i[100 + pass];
    if ((int)blockIdx.y >= nt) return;
    const int tile = ws_i[(pass ? 896 : 768) + blockIdx.y];
    const int e   = tile >> 16;
    const int rbl = tile & 0xFFFF;
    const int dc  = blockIdx.x;
    const int ab  = pass * NP1 + rbl;

    __shared__ u16   as_[64][72];
    __shared__ u16   wt2[128][72];
    __shared__ int   entL[64];
    __shared__ float gateL[64];

    const int tid = threadIdx.x;
    if (tid < 64) {
        const int ent = entries[rbl + tid];
        entL[tid]  = ent;
        gateL[tid] = (ent < 0) ? 0.f : top_g[ent];
    }
    __syncthreads();

    const int wid = tid >> 6;
    const int ln  = tid & 63;
    const int qd  = ln >> 4;
    const int lm  = ln & 15;
    const int r8  = tid >> 3;
    const int seg = tid & 7;

    const u16* wbase = wob + ((size_t)e << 19) + ((size_t)(dc << 7) << 9);

    f32x4 acc[4][2];
    #pragma unroll
    for (int i = 0; i < 4; ++i)
        #pragma unroll
        for (int j = 0; j < 2; ++j) acc[i][j] = (f32x4){0.f,0.f,0.f,0.f};

    for (int k0 = 0; k0 < 512; k0 += 64) {
        uint4 av0, av1, wv[4];
        av0 = *(const uint4*)(act + ((size_t)(ab + r8) << 9) + k0 + seg * 8);
        av1 = *(const uint4*)(act + ((size_t)(ab + 32 + r8) << 9) + k0 + seg * 8);
        #pragma unroll
        for (int s = 0; s < 4; ++s)
            wv[s] = *(const uint4*)(wbase + ((size_t)(s * 32 + r8) << 9) + k0 + seg * 8);
        __syncthreads();
        *(uint4*)&as_[r8][seg * 8]      = av0;
        *(uint4*)&as_[32 + r8][seg * 8] = av1;
        #pragma unroll
        for (int s = 0; s < 4; ++s)
            *(uint4*)&wt2[s * 32 + r8][seg * 8] = wv[s];
        __syncthreads();
        #pragma unroll
        for (int ki = 0; ki < 2; ++ki) {
            const int ko = ki * 32 + (qd << 3);
            const bf16x8 b0 = LDF(wt2, (wid << 5) + lm, ko);
            const bf16x8 b1 = LDF(wt2, (wid << 5) + 16 + lm, ko);
            #pragma unroll
            for (int i = 0; i < 4; ++i) {
                const bf16x8 aF = LDF(as_, (i << 4) + lm, ko);
                acc[i][0] = MFMA(aF, b0, acc[i][0]);
                acc[i][1] = MFMA(aF, b1, acc[i][1]);
            }
        }
    }

    #pragma unroll
    for (int i = 0; i < 4; ++i) {
        #pragma unroll
        for (int j = 0; j < 2; ++j) {
            #pragma unroll
            for (int r = 0; r < 4; ++r) {
                const int row = (i << 4) + (qd << 2) + r;
                const int ent = entL[row];
                if (ent >= 0) {
                    const int t   = ent >> 1;
                    const int col = (dc << 7) + (wid << 5) + (j << 4) + lm;
                    float* po = out + ((size_t)t << 10) + col;
                    float vv = gateL[row] * acc[i][j][r];
                    if (pass) vv += *po;
                    *po = vv;
                }
            }
        }
    }
}

// ================== fp32-staged MFMA fallback (R6, proven; ws in [9.6,43) MB) ==================
__global__ __launch_bounds__(256) void g1_mfma(
    const float* __restrict__ x, const float* __restrict__ w_in,
    const int* __restrict__ ws_i, const int* __restrict__ e0,
    const int* __restrict__ e1, u16* __restrict__ act)
{
    const int nt = ws_i[99];
    if ((int)blockIdx.y >= nt) return;
    const int tile = ws_i[512 + blockIdx.y];
    const int e  = tile >> 16;
    const int rb = tile & 0xFFFF;
    const int nc = blockIdx.x;

    __shared__ u16 xs[64][72];
    __shared__ u16 wt[128][72];
    __shared__ int tokL[64];

    const int tid = threadIdx.x;
    if (tid < 64) {
        const int ent = (rb >= NP1) ? e1[rb - NP1 + tid] : e0[rb + tid];
        tokL[tid] = (ent < 0) ? 0 : (ent >> 1);
    }
    __syncthreads();

    const int wid = tid >> 6;
    const int ln  = tid & 63;
    const int qd  = ln >> 4;
    const int lm  = ln & 15;
    const int srow = tid >> 4;
    const int sseg = tid & 15;

    int xtok[4];
    #pragma unroll
    for (int s = 0; s < 4; ++s) xtok[s] = tokL[s * 16 + srow];

    f32x4 accA[4], accB[4];
    #pragma unroll
    for (int i = 0; i < 4; ++i) { accA[i] = (f32x4){0.f,0.f,0.f,0.f}; accB[i] = (f32x4){0.f,0.f,0.f,0.f}; }

    for (int k0 = 0; k0 < 1024; k0 += 64) {
        float4 xv[4], wvv[8];
        #pragma unroll
        for (int s = 0; s < 4; ++s)
            xv[s] = *(const float4*)(x + ((size_t)xtok[s] << 10) + k0 + (sseg << 2));
        #pragma unroll
        for (int s = 0; s < 8; ++s) {
            const int row = s * 16 + srow;
            const int wr  = (row < 64) ? (nc * 64 + row) : (448 + nc * 64 + row);
            wvv[s] = *(const float4*)(w_in + ((size_t)e << 20) + ((size_t)wr << 10) + k0 + (sseg << 2));
        }
        __syncthreads();
        #pragma unroll
        for (int s = 0; s < 4; ++s) {
            uint2 pk; pk.x = pk2(xv[s].x, xv[s].y); pk.y = pk2(xv[s].z, xv[s].w);
            *(uint2*)&xs[s * 16 + srow][sseg << 2] = pk;
        }
        #pragma unroll
        for (int s = 0; s < 8; ++s) {
            uint2 pk; pk.x = pk2(wvv[s].x, wvv[s].y); pk.y = pk2(wvv[s].z, wvv[s].w);
            *(uint2*)&wt[s * 16 + srow][sseg << 2] = pk;
        }
        __syncthreads();
        #pragma unroll
        for (int ki = 0; ki < 2; ++ki) {
            const int ko = ki * 32 + (qd << 3);
            const bf16x8 bA = LDF(wt, (wid << 4) + lm, ko);
            const bf16x8 bB = LDF(wt, 64 + (wid << 4) + lm, ko);
            #pragma unroll
            for (int i = 0; i < 4; ++i) {
                const bf16x8 aF = LDF(xs, (i << 4) + lm, ko);
                accA[i] = MFMA(aF, bA, accA[i]);
                accB[i] = MFMA(aF, bB, accB[i]);
            }
        }
    }

    #pragma unroll
    for (int i = 0; i < 4; ++i) {
        #pragma unroll
        for (int r = 0; r < 4; ++r) {
            const float a = accA[i][r], b = accB[i][r];
            const float v = b * a / (1.f + __expf(-a));
            const int row = (i << 4) + (qd << 2) + r;
            act[((size_t)(rb + row) << 9) + (nc << 6) + (wid << 4) + lm] = f2bf(v);
        }
    }
}

__global__ __launch_bounds__(256) void g2_mfma(
    const u16* __restrict__ act, const float* __restrict__ w_out,
    const int* __restrict__ ws_i, const int* __restrict__ entries,
    const float* __restrict__ top_g, float* __restrict__ out, int pass)
{
    const int nt = ws_i[100 + pass];
    if ((int)blockIdx.y >= nt) return;
    const int tile = ws_i[(pass ? 896 : 768) + blockIdx.y];
    const int e   = tile >> 16;
    const int rbl = tile & 0xFFFF;
    const int dc  = blockIdx.x;
    const int ab  = pass * NP1 + rbl;

    __shared__ u16   as_[64][72];
    __shared__ u16   wt2[128][72];
    __shared__ int   entL[64];
    __shared__ float gateL[64];

    const int tid = threadIdx.x;
    if (tid < 64) {
        const int ent = entries[rbl + tid];
        entL[tid]  = ent;
        gateL[tid] = (ent < 0) ? 0.f : top_g[ent];
    }
    __syncthreads();

    const int wid = tid >> 6;
    const int ln  = tid & 63;
    const int qd  = ln >> 4;
    const int lm  = ln & 15;
    const int srow = tid >> 4;
    const int sseg = tid & 15;

    f32x4 acc[4][2];
    #pragma unroll
    for (int i = 0; i < 4; ++i)
        #pragma unroll
        for (int j = 0; j < 2; ++j) acc[i][j] = (f32x4){0.f,0.f,0.f,0.f};

    for (int k0 = 0; k0 < 512; k0 += 64) {
        uint4 av[2];
        float4 wvv[8];
        #pragma unroll
        for (int s = 0; s < 2; ++s) {
            const int idx = (s << 8) + tid;
            av[s] = *(const uint4*)(act + ((size_t)(ab + (idx >> 3)) << 9) + k0 + ((idx & 7) << 3));
        }
        #pragma unroll
        for (int s = 0; s < 8; ++s) {
            const int row = s * 16 + srow;
            wvv[s] = *(const float4*)(w_out + ((size_t)e << 19) + ((size_t)((dc << 7) + row) << 9) + k0 + (sseg << 2));
        }
        __syncthreads();
        #pragma unroll
        for (int s = 0; s < 2; ++s) {
            const int idx = (s << 8) + tid;
            *(uint4*)&as_[idx >> 3][(idx & 7) << 3] = av[s];
        }
        #pragma unroll
        for (int s = 0; s < 8; ++s) {
            uint2 pk; pk.x = pk2(wvv[s].x, wvv[s].y); pk.y = pk2(wvv[s].z, wvv[s].w);
            *(uint2*)&wt2[s * 16 + srow][sseg << 2] = pk;
        }
        __syncthreads();
        #pragma unroll
        for (int ki = 0; ki < 2; ++ki) {
            const int ko = ki * 32 + (qd << 3);
            const bf16x8 b0 = LDF(wt2, (wid << 5) + lm, ko);
            const bf16x8 b1 = LDF(wt2, (wid << 5) + 16 + lm, ko);
            #pragma unroll
            for (int i = 0; i < 4; ++i) {
                const bf16x8 aF = LDF(as_, (i << 4) + lm, ko);
                acc[i][0] = MFMA(aF, b0, acc[i][0]);
                acc[i][1] = MFMA(aF, b1, acc[i][1]);
            }
        }
    }

    #pragma unroll
    for (int i = 0; i < 4; ++i) {
        #pragma unroll
        for (int j = 0; j < 2; ++j) {
            #pragma unroll
            for (int r = 0; r < 4; ++r) {
                const int row = (i << 4) + (qd << 2) + r;
                const int ent = entL[row];
                if (ent >= 0) {
                    const int t   = ent >> 1;
                    const int col = (dc << 7) + (wid << 5) + (j << 4) + lm;
                    float* po = out + ((size_t)t << 10) + col;
                    float vv = gateL[row] * acc[i][j][r];
                    if (pass) vv += *po;
                    *po = vv;
                }
            }
        }
    }
}

extern "C" void kernel_launch(void* const* d_in, const int* in_sizes, int n_in,
                              void* d_out, int out_size, void* d_ws, size_t ws_size,
                              hipStream_t stream)
{
    (void)in_sizes; (void)n_in; (void)out_size;
    const float* x     = (const float*)d_in[0];   // [4096,1024] fp32
    const float* wr    = (const float*)d_in[1];   // [8,1024]
    const float* w_in  = (const float*)d_in[2];   // [8,1024,1024]
    const float* w_out = (const float*)d_in[3];   // [8,1024,512]
    float* out = (float*)d_out;                   // [4096*1024] out ++ [4096*8] logits

    char* ws = (char*)d_ws;
    int*   ws_i  = (int*)ws;                          //  4 KB control + tables
    int*   e0    = (int*)(ws + 8192);
    int*   e1    = (int*)(ws + 26624);
    int*   top_e = (int*)(ws + 45056);
    float* top_g = (float*)(ws + 77824);
    u16*   act   = (u16*)(ws + 131072);               //  9.4 MB
    u16*   xb    = (u16*)(ws + 9568256);              //  8 MB   (big-ws only)
    u16*   wib   = (u16*)(ws + 17956864);             // 16 MB   (big-ws only)
    u16*   wob   = (u16*)(ws + 34734080);             //  8 MB   (big-ws only)

    const bool big = (ws_size >= BIG_WS);

    router_kernel<<<256, 256, 0, stream>>>(x, wr, out + (size_t)T_TOK * D_DIM,
                                           top_e, top_g, big ? xb : (u16*)nullptr);
    countscan_kernel<<<1, 256, 0, stream>>>(top_e, ws_i, e0, e1);
    scatter_kernel<<<32, 256, 0, stream>>>(top_e, ws_i, e0, e1);

    if (big) {
        conv_kernel<<<1024, 256, 0, stream>>>(w_in, w_out, wib, wob);
        g1_mfma_b<<<dim3(8, 144), 256, 0, stream>>>(xb, wib, ws_i, e0, e1, act);
        g2_mfma_b<<<dim3(8, 72), 256, 0, stream>>>(act, wob, ws_i, e0, top_g, out, 0);
        g2_mfma_b<<<dim3(8, 72), 256, 0, stream>>>(act, wob, ws_i, e1, top_g, out, 1);
    } else {
        g1_mfma<<<dim3(8, 144), 256, 0, stream>>>(x, w_in, ws_i, e0, e1, act);
        g2_mfma<<<dim3(8, 72), 256, 0, stream>>>(act, w_out, ws_i, e0, top_g, out, 0);
        g2_mfma<<<dim3(8, 72), 256, 0, stream>>>(act, w_out, ws_i, e1, top_g, out, 1);
    }
}

// Round 8
// 250.529 us; speedup vs baseline: 1.3005x; 1.3005x over previous
//
#include <hip/hip_runtime.h>

typedef unsigned short u16;
typedef unsigned int   u32;

#define T_TOK 4096
#define D_DIM 1024
#define H_DIM 512
#define E_NUM 8
#define NP1   4608        // padded entries per pass (buckets padded to 64)
#define MAXP  4608

typedef __bf16 bf16x8 __attribute__((ext_vector_type(8)));
typedef float  f32x4  __attribute__((ext_vector_type(4)));

// ---------- bf16 helpers (native cvt: v_cvt_pk_bf16_f32 on gfx950) ----------
__device__ __forceinline__ u16 f2bf(float f) {
    return __builtin_bit_cast(u16, (__bf16)f);
}
__device__ __forceinline__ u32 pk2(float a, float b) {
    return (u32)f2bf(a) | ((u32)f2bf(b) << 16);
}
__device__ __forceinline__ float blo(u32 v) { return __uint_as_float(v << 16); }
__device__ __forceinline__ float bhi(u32 v) { return __uint_as_float(v & 0xffff0000u); }

#define LDF(arr, r, koff) __builtin_bit_cast(bf16x8, *(const uint4*)(&arr[r][koff]))
#define MFMA(a, b, c) __builtin_amdgcn_mfma_f32_16x16x32_bf16(a, b, c, 0, 0, 0)

// ---------- router: logits + top-2 gates; no atomics ----------
__global__ __launch_bounds__(256) void router_kernel(
    const float* __restrict__ x, const float* __restrict__ wr,
    float* __restrict__ logits_out, int* __restrict__ top_e, float* __restrict__ top_g)
{
    __shared__ float wrL[E_NUM][1024];
    const int tid = threadIdx.x;
    #pragma unroll
    for (int i = 0; i < 8; ++i) {
        const int idx = (i * 256 + tid) * 4;
        *(float4*)&wrL[0][idx] = *(const float4*)(wr + idx);
    }
    __syncthreads();

    const int lane = tid & 63;
    const int wv   = tid >> 6;
    const int t0   = blockIdx.x * 16 + wv * 4;

    for (int tt = 0; tt < 4; ++tt) {
        const int t = t0 + tt;
        const float* xr = x + ((size_t)t << 10);
        float4 xv[4];
        #pragma unroll
        for (int j = 0; j < 4; ++j)
            xv[j] = *(const float4*)(xr + j * 256 + lane * 4);

        float acc[E_NUM];
        #pragma unroll
        for (int e = 0; e < E_NUM; ++e) acc[e] = 0.f;
        #pragma unroll
        for (int j = 0; j < 4; ++j) {
            #pragma unroll
            for (int e = 0; e < E_NUM; ++e) {
                const float4 w4 = *(const float4*)&wrL[e][j * 256 + lane * 4];
                acc[e] += xv[j].x * w4.x + xv[j].y * w4.y + xv[j].z * w4.z + xv[j].w * w4.w;
            }
        }
        #pragma unroll
        for (int off = 32; off >= 1; off >>= 1) {
            #pragma unroll
            for (int e = 0; e < E_NUM; ++e)
                acc[e] += __shfl_xor(acc[e], off);
        }
        if (lane == 0) {
            #pragma unroll
            for (int e = 0; e < E_NUM; ++e)
                logits_out[t * E_NUM + e] = acc[e];
            int i0 = 0; float v0 = acc[0];
            #pragma unroll
            for (int e = 1; e < E_NUM; ++e) { if (acc[e] > v0) { v0 = acc[e]; i0 = e; } }
            int i1 = (i0 == 0) ? 1 : 0; float v1 = acc[i1];
            #pragma unroll
            for (int e = 0; e < E_NUM; ++e) { if (e != i0 && e != i1 && acc[e] > v1) { v1 = acc[e]; i1 = e; } }
            const float ed = __expf(v1 - v0);
            const float g0 = 1.f / (1.f + ed);
            top_e[2 * t]     = i0;  top_e[2 * t + 1] = i1;
            top_g[2 * t]     = g0;  top_g[2 * t + 1] = 1.f - g0;
        }
    }
}

// ---------- countscan: prefill entries, LDS histogram, offsets/cursors, tile table ----------
// ws_i: [0..15] counts, [64..79] local offsets, [99] ntiles,
//       cursors PADDED at [128+16*b], tile table @512 (<=144): (e<<16)|rb_global
__global__ __launch_bounds__(256) void countscan_kernel(
    const int* __restrict__ top_e, int* __restrict__ ws_i,
    int* __restrict__ e0, int* __restrict__ e1)
{
    __shared__ int hist[16];
    const int tid = threadIdx.x;
    if (tid < 16) hist[tid] = 0;
    for (int i = tid; i < MAXP; i += 256) { e0[i] = -1; e1[i] = -1; }
    __syncthreads();
    for (int i = tid; i < 2 * T_TOK; i += 256) {
        const int e = top_e[i] & 7;
        atomicAdd(&hist[2 * e + (i & 1)], 1);
    }
    __syncthreads();
    if (tid == 0) {
        int nt = 0;
        for (int k = 0; k < 2; ++k) {
            int s = 0;
            for (int e = 0; e < E_NUM; ++e) {
                const int b = 2 * e + k;
                const int c = hist[b];
                ws_i[b]            = c;
                ws_i[64 + b]       = s;
                ws_i[128 + 16 * b] = s;
                const int pc = (c + 63) & ~63;
                for (int j = 0; j < pc / 64 && nt < 144; ++j)
                    ws_i[512 + nt++] = (e << 16) | (k * NP1 + s + j * 64);
                s += pc;
            }
        }
        ws_i[99] = nt;
    }
}

// ---------- scatter: padded cursors + token->row inverse map ----------
__global__ __launch_bounds__(256) void scatter_kernel(
    const int* __restrict__ top_e, int* __restrict__ ws_i,
    int* __restrict__ e0, int* __restrict__ e1, int* __restrict__ posmap)
{
    const int idx = blockIdx.x * 256 + threadIdx.x;  // idx = 2*t + k
    const int e   = top_e[idx] & 7;
    const int k   = idx & 1;
    const int b   = 2 * e + k;
    int pos = atomicAdd(&ws_i[128 + 16 * b], 1);
    if (pos >= MAXP) pos = MAXP - 1;
    (k ? e1 : e0)[pos] = idx;
    posmap[idx] = pos;
}

// ---------- g1 (pipelined): act = swiglu(x @ w_in[e]^T), M=64, N=128 wrows, K=1024 ----------
__global__ __launch_bounds__(256, 2) void g1_p(
    const float* __restrict__ x, const float* __restrict__ w_in,
    const int* __restrict__ ws_i, const int* __restrict__ e0,
    const int* __restrict__ e1, u16* __restrict__ act)
{
    const int nt = ws_i[99];
    if ((int)blockIdx.y >= nt) return;
    const int tile = ws_i[512 + blockIdx.y];
    const int e  = tile >> 16;
    const int rb = tile & 0xFFFF;        // global padded row base
    const int nc = blockIdx.x;

    __shared__ u16 xs[2][64][72];
    __shared__ u16 wt[2][128][72];
    __shared__ int tokL[64];

    const int tid = threadIdx.x;
    if (tid < 64) {
        const int ent = (rb >= NP1) ? e1[rb - NP1 + tid] : e0[rb + tid];
        tokL[tid] = (ent < 0) ? 0 : (ent >> 1);
    }
    __syncthreads();

    const int wid = tid >> 6, ln = tid & 63, qd = ln >> 4, lm = ln & 15;
    const int srow = tid >> 4, sseg = tid & 15;

    int xtok[4];
    #pragma unroll
    for (int s = 0; s < 4; ++s) xtok[s] = tokL[s * 16 + srow];
    int wrow[8];
    #pragma unroll
    for (int s = 0; s < 8; ++s) {
        const int row = s * 16 + srow;
        wrow[s] = (row < 64) ? (nc * 64 + row) : (448 + nc * 64 + row);
    }
    const float* wbase = w_in + ((size_t)e << 20);

    float4 xv[4], wv[8];
    // preload iter 0 -> buf0
    #pragma unroll
    for (int s = 0; s < 4; ++s)
        xv[s] = *(const float4*)(x + ((size_t)xtok[s] << 10) + (sseg << 2));
    #pragma unroll
    for (int s = 0; s < 8; ++s)
        wv[s] = *(const float4*)(wbase + ((size_t)wrow[s] << 10) + (sseg << 2));
    #pragma unroll
    for (int s = 0; s < 4; ++s) {
        uint2 p; p.x = pk2(xv[s].x, xv[s].y); p.y = pk2(xv[s].z, xv[s].w);
        *(uint2*)&xs[0][s * 16 + srow][sseg << 2] = p;
    }
    #pragma unroll
    for (int s = 0; s < 8; ++s) {
        uint2 p; p.x = pk2(wv[s].x, wv[s].y); p.y = pk2(wv[s].z, wv[s].w);
        *(uint2*)&wt[0][s * 16 + srow][sseg << 2] = p;
    }
    __syncthreads();

    f32x4 accA[4], accB[4];
    #pragma unroll
    for (int i = 0; i < 4; ++i) { accA[i] = (f32x4){0.f,0.f,0.f,0.f}; accB[i] = (f32x4){0.f,0.f,0.f,0.f}; }

    #pragma unroll 2
    for (int it = 0; it < 16; ++it) {
        const int cur = it & 1;
        if (it < 15) {   // issue next-iter loads BEFORE compute; vmcnt wait lands at the store
            const int k1 = (it + 1) << 6;
            #pragma unroll
            for (int s = 0; s < 4; ++s)
                xv[s] = *(const float4*)(x + ((size_t)xtok[s] << 10) + k1 + (sseg << 2));
            #pragma unroll
            for (int s = 0; s < 8; ++s)
                wv[s] = *(const float4*)(wbase + ((size_t)wrow[s] << 10) + k1 + (sseg << 2));
        }
        #pragma unroll
        for (int ki = 0; ki < 2; ++ki) {
            const int ko = ki * 32 + (qd << 3);
            const bf16x8 bA = LDF(wt[cur], (wid << 4) + lm, ko);
            const bf16x8 bB = LDF(wt[cur], 64 + (wid << 4) + lm, ko);
            #pragma unroll
            for (int i = 0; i < 4; ++i) {
                const bf16x8 aF = LDF(xs[cur], (i << 4) + lm, ko);
                accA[i] = MFMA(aF, bA, accA[i]);
                accB[i] = MFMA(aF, bB, accB[i]);
            }
        }
        if (it < 15) {
            const int nb = cur ^ 1;
            #pragma unroll
            for (int s = 0; s < 4; ++s) {
                uint2 p; p.x = pk2(xv[s].x, xv[s].y); p.y = pk2(xv[s].z, xv[s].w);
                *(uint2*)&xs[nb][s * 16 + srow][sseg << 2] = p;
            }
            #pragma unroll
            for (int s = 0; s < 8; ++s) {
                uint2 p; p.x = pk2(wv[s].x, wv[s].y); p.y = pk2(wv[s].z, wv[s].w);
                *(uint2*)&wt[nb][s * 16 + srow][sseg << 2] = p;
            }
        }
        __syncthreads();
    }

    #pragma unroll
    for (int i = 0; i < 4; ++i) {
        #pragma unroll
        for (int r = 0; r < 4; ++r) {
            const float a = accA[i][r], b = accB[i][r];
            const float v = b * a / (1.f + __expf(-a));
            const int row = (i << 4) + (qd << 2) + r;
            act[((size_t)(rb + row) << 9) + (nc << 6) + (wid << 4) + lm] = f2bf(v);
        }
    }
}

// ---------- g2 (pipelined, single launch): y[row] = gate * (act @ w_out[e]^T), M=64, N=128, K=512 ----------
__global__ __launch_bounds__(256, 2) void g2_p(
    const u16* __restrict__ act, const float* __restrict__ w_out,
    const int* __restrict__ ws_i, const int* __restrict__ e0,
    const int* __restrict__ e1, const float* __restrict__ top_g,
    u16* __restrict__ y)
{
    const int nt = ws_i[99];
    if ((int)blockIdx.y >= nt) return;
    const int tile = ws_i[512 + blockIdx.y];
    const int e  = tile >> 16;
    const int rb = tile & 0xFFFF;        // global padded row base
    const int dc = blockIdx.x;

    __shared__ u16   as_[2][64][72];
    __shared__ u16   wt2[2][128][72];
    __shared__ float gateL[64];

    const int tid = threadIdx.x;
    if (tid < 64) {
        const int ent = (rb >= NP1) ? e1[rb - NP1 + tid] : e0[rb + tid];
        gateL[tid] = (ent < 0) ? 0.f : top_g[ent];
    }
    __syncthreads();

    const int wid = tid >> 6, ln = tid & 63, qd = ln >> 4, lm = ln & 15;
    const int srow = tid >> 4, sseg = tid & 15;
    const int arow0 = tid >> 3, aseg0 = tid & 7;             // act staging map (s=0)
    const int arow1 = (256 + tid) >> 3, aseg1 = tid & 7;     // s=1

    const float* wbase = w_out + ((size_t)e << 19) + ((size_t)(dc << 7) << 9);

    uint4 av[2];
    float4 wv[8];
    // preload iter 0 -> buf0
    av[0] = *(const uint4*)(act + ((size_t)(rb + arow0) << 9) + (aseg0 << 3));
    av[1] = *(const uint4*)(act + ((size_t)(rb + arow1) << 9) + (aseg1 << 3));
    #pragma unroll
    for (int s = 0; s < 8; ++s)
        wv[s] = *(const float4*)(wbase + ((size_t)(s * 16 + srow) << 9) + (sseg << 2));
    *(uint4*)&as_[0][arow0][aseg0 << 3] = av[0];
    *(uint4*)&as_[0][arow1][aseg1 << 3] = av[1];
    #pragma unroll
    for (int s = 0; s < 8; ++s) {
        uint2 p; p.x = pk2(wv[s].x, wv[s].y); p.y = pk2(wv[s].z, wv[s].w);
        *(uint2*)&wt2[0][s * 16 + srow][sseg << 2] = p;
    }
    __syncthreads();

    f32x4 acc[4][2];
    #pragma unroll
    for (int i = 0; i < 4; ++i)
        #pragma unroll
        for (int j = 0; j < 2; ++j) acc[i][j] = (f32x4){0.f,0.f,0.f,0.f};

    #pragma unroll 2
    for (int it = 0; it < 8; ++it) {
        const int cur = it & 1;
        if (it < 7) {
            const int k1 = (it + 1) << 6;
            av[0] = *(const uint4*)(act + ((size_t)(rb + arow0) << 9) + k1 + (aseg0 << 3));
            av[1] = *(const uint4*)(act + ((size_t)(rb + arow1) << 9) + k1 + (aseg1 << 3));
            #pragma unroll
            for (int s = 0; s < 8; ++s)
                wv[s] = *(const float4*)(wbase + ((size_t)(s * 16 + srow) << 9) + k1 + (sseg << 2));
        }
        #pragma unroll
        for (int ki = 0; ki < 2; ++ki) {
            const int ko = ki * 32 + (qd << 3);
            const bf16x8 b0 = LDF(wt2[cur], (wid << 5) + lm, ko);
            const bf16x8 b1 = LDF(wt2[cur], (wid << 5) + 16 + lm, ko);
            #pragma unroll
            for (int i = 0; i < 4; ++i) {
                const bf16x8 aF = LDF(as_[cur], (i << 4) + lm, ko);
                acc[i][0] = MFMA(aF, b0, acc[i][0]);
                acc[i][1] = MFMA(aF, b1, acc[i][1]);
            }
        }
        if (it < 7) {
            const int nb = cur ^ 1;
            *(uint4*)&as_[nb][arow0][aseg0 << 3] = av[0];
            *(uint4*)&as_[nb][arow1][aseg1 << 3] = av[1];
            #pragma unroll
            for (int s = 0; s < 8; ++s) {
                uint2 p; p.x = pk2(wv[s].x, wv[s].y); p.y = pk2(wv[s].z, wv[s].w);
                *(uint2*)&wt2[nb][s * 16 + srow][sseg << 2] = p;
            }
        }
        __syncthreads();
    }

    #pragma unroll
    for (int i = 0; i < 4; ++i) {
        #pragma unroll
        for (int j = 0; j < 2; ++j) {
            #pragma unroll
            for (int r = 0; r < 4; ++r) {
                const int row = (i << 4) + (qd << 2) + r;
                const int col = (dc << 7) + (wid << 5) + (j << 4) + lm;
                y[((size_t)(rb + row) << 10) + col] = f2bf(gateL[row] * acc[i][j][r]);
            }
        }
    }
}

// ---------- combine: out[t] = y[pos0[t]] + y[NP1 + pos1[t]] ----------
__global__ __launch_bounds__(256) void combine_kernel(
    const u16* __restrict__ y, const int* __restrict__ posmap,
    float* __restrict__ out)
{
    const int idx = blockIdx.x * 256 + threadIdx.x;   // 524288 total
    const int t  = idx >> 7;
    const int c8 = (idx & 127) << 3;
    const int r0 = posmap[2 * t];
    const int r1 = NP1 + posmap[2 * t + 1];
    const uint4 a = *(const uint4*)(y + ((size_t)r0 << 10) + c8);
    const uint4 b = *(const uint4*)(y + ((size_t)r1 << 10) + c8);
    float4 o0, o1;
    o0.x = blo(a.x) + blo(b.x); o0.y = bhi(a.x) + bhi(b.x);
    o0.z = blo(a.y) + blo(b.y); o0.w = bhi(a.y) + bhi(b.y);
    o1.x = blo(a.z) + blo(b.z); o1.y = bhi(a.z) + bhi(b.z);
    o1.z = blo(a.w) + blo(b.w); o1.w = bhi(a.w) + bhi(b.w);
    float* po = out + ((size_t)t << 10) + c8;
    *(float4*)po       = o0;
    *(float4*)(po + 4) = o1;
}

extern "C" void kernel_launch(void* const* d_in, const int* in_sizes, int n_in,
                              void* d_out, int out_size, void* d_ws, size_t ws_size,
                              hipStream_t stream)
{
    (void)in_sizes; (void)n_in; (void)out_size; (void)ws_size;
    const float* x     = (const float*)d_in[0];   // [4096,1024] fp32
    const float* wr    = (const float*)d_in[1];   // [8,1024]
    const float* w_in  = (const float*)d_in[2];   // [8,1024,1024]
    const float* w_out = (const float*)d_in[3];   // [8,1024,512]
    float* out = (float*)d_out;                   // [4096*1024] out ++ [4096*8] logits

    char* ws = (char*)d_ws;                           // ~28.5 MB total (ws >= 43 MB proven R7)
    int*   ws_i   = (int*)ws;                         //  4 KB control + tile table
    int*   e0     = (int*)(ws + 8192);                // 18 KB entries pass 0
    int*   e1     = (int*)(ws + 26624);               // 18 KB entries pass 1
    int*   top_e  = (int*)(ws + 45056);               // 32 KB
    float* top_g  = (float*)(ws + 77824);             // 32 KB
    int*   posmap = (int*)(ws + 110592);              // 32 KB token->bucket-row
    u16*   act    = (u16*)(ws + 147456);              // 9216*512*2  = 9.4 MB
    u16*   y      = (u16*)(ws + 147456 + (size_t)9216 * 512 * 2);  // 9216*1024*2 = 18.9 MB

    router_kernel<<<256, 256, 0, stream>>>(x, wr, out + (size_t)T_TOK * D_DIM, top_e, top_g);
    countscan_kernel<<<1, 256, 0, stream>>>(top_e, ws_i, e0, e1);
    scatter_kernel<<<32, 256, 0, stream>>>(top_e, ws_i, e0, e1, posmap);
    g1_p<<<dim3(8, 144), 256, 0, stream>>>(x, w_in, ws_i, e0, e1, act);
    g2_p<<<dim3(8, 144), 256, 0, stream>>>(act, w_out, ws_i, e0, e1, top_g, y);
    combine_kernel<<<2048, 256, 0, stream>>>(y, posmap, out);
}

// Round 9
// 237.564 us; speedup vs baseline: 1.3714x; 1.0546x over previous
//
#include <hip/hip_runtime.h>

typedef unsigned short u16;
typedef unsigned int   u32;

#define T_TOK 4096
#define D_DIM 1024
#define H_DIM 512
#define E_NUM 8
#define NP1   5120        // padded entries per pass (buckets padded to 128)
#define MAXP  5120

typedef __bf16 bf16x8 __attribute__((ext_vector_type(8)));
typedef float  f32x4  __attribute__((ext_vector_type(4)));

__device__ __forceinline__ u16 f2bf(float f) {
    return __builtin_bit_cast(u16, (__bf16)f);
}
__device__ __forceinline__ u32 pk2(float a, float b) {
    return (u32)f2bf(a) | ((u32)f2bf(b) << 16);
}
__device__ __forceinline__ float blo(u32 v) { return __uint_as_float(v << 16); }
__device__ __forceinline__ float bhi(u32 v) { return __uint_as_float(v & 0xffff0000u); }

#define LDF(arr, r, koff) __builtin_bit_cast(bf16x8, *(const uint4*)(&arr[r][koff]))
#define MFMA(a, b, c) __builtin_amdgcn_mfma_f32_16x16x32_bf16(a, b, c, 0, 0, 0)

// ---------- router: logits + top-2 gates; no atomics ----------
__global__ __launch_bounds__(256) void router_kernel(
    const float* __restrict__ x, const float* __restrict__ wr,
    float* __restrict__ logits_out, int* __restrict__ top_e, float* __restrict__ top_g)
{
    __shared__ float wrL[E_NUM][1024];
    const int tid = threadIdx.x;
    #pragma unroll
    for (int i = 0; i < 8; ++i) {
        const int idx = (i * 256 + tid) * 4;
        *(float4*)&wrL[0][idx] = *(const float4*)(wr + idx);
    }
    __syncthreads();

    const int lane = tid & 63;
    const int wv   = tid >> 6;
    const int t0   = blockIdx.x * 16 + wv * 4;

    for (int tt = 0; tt < 4; ++tt) {
        const int t = t0 + tt;
        const float* xr = x + ((size_t)t << 10);
        float4 xv[4];
        #pragma unroll
        for (int j = 0; j < 4; ++j)
            xv[j] = *(const float4*)(xr + j * 256 + lane * 4);

        float acc[E_NUM];
        #pragma unroll
        for (int e = 0; e < E_NUM; ++e) acc[e] = 0.f;
        #pragma unroll
        for (int j = 0; j < 4; ++j) {
            #pragma unroll
            for (int e = 0; e < E_NUM; ++e) {
                const float4 w4 = *(const float4*)&wrL[e][j * 256 + lane * 4];
                acc[e] += xv[j].x * w4.x + xv[j].y * w4.y + xv[j].z * w4.z + xv[j].w * w4.w;
            }
        }
        #pragma unroll
        for (int off = 32; off >= 1; off >>= 1) {
            #pragma unroll
            for (int e = 0; e < E_NUM; ++e)
                acc[e] += __shfl_xor(acc[e], off);
        }
        if (lane == 0) {
            #pragma unroll
            for (int e = 0; e < E_NUM; ++e)
                logits_out[t * E_NUM + e] = acc[e];
            int i0 = 0; float v0 = acc[0];
            #pragma unroll
            for (int e = 1; e < E_NUM; ++e) { if (acc[e] > v0) { v0 = acc[e]; i0 = e; } }
            int i1 = (i0 == 0) ? 1 : 0; float v1 = acc[i1];
            #pragma unroll
            for (int e = 0; e < E_NUM; ++e) { if (e != i0 && e != i1 && acc[e] > v1) { v1 = acc[e]; i1 = e; } }
            const float ed = __expf(v1 - v0);
            const float g0 = 1.f / (1.f + ed);
            top_e[2 * t]     = i0;  top_e[2 * t + 1] = i1;
            top_g[2 * t]     = g0;  top_g[2 * t + 1] = 1.f - g0;
        }
    }
}

// ---------- prep: prefill + histogram + offsets/tables + scatter, one block ----------
// ws_i: [0..15] counts, [64..79] local offsets, [99] ntiles,
//       tile table @512 (<=128 entries): (e<<16) | rb_global  (rb mult of 128)
__global__ __launch_bounds__(256) void prep_kernel(
    const int* __restrict__ top_e, int* __restrict__ ws_i,
    int* __restrict__ e0, int* __restrict__ e1, int* __restrict__ posmap)
{
    __shared__ int hist[16];
    __shared__ int cur[16];
    const int tid = threadIdx.x;
    if (tid < 16) hist[tid] = 0;
    for (int i = tid; i < MAXP; i += 256) { e0[i] = -1; e1[i] = -1; }
    __syncthreads();
    for (int i = tid; i < 2 * T_TOK; i += 256)
        atomicAdd(&hist[2 * (top_e[i] & 7) + (i & 1)], 1);
    __syncthreads();
    if (tid == 0) {
        int nt = 0;
        for (int k = 0; k < 2; ++k) {
            int s = 0;
            for (int e = 0; e < E_NUM; ++e) {
                const int b = 2 * e + k;
                const int c = hist[b];
                ws_i[b]      = c;
                ws_i[64 + b] = s;
                cur[b]       = s;
                const int pc = (c + 127) & ~127;
                for (int j = 0; j < pc / 128 && nt < 128; ++j)
                    ws_i[512 + nt++] = (e << 16) | (k * NP1 + s + j * 128);
                s += pc;
            }
        }
        ws_i[99] = nt;
    }
    __syncthreads();
    for (int i = tid; i < 2 * T_TOK; i += 256) {
        const int b   = 2 * (top_e[i] & 7) + (i & 1);
        const int pos = atomicAdd(&cur[b], 1);
        ((i & 1) ? e1 : e0)[pos] = i;
        posmap[i] = pos;
    }
}

// ---------- g1: 128x128 tile, act = swiglu(x @ w_in[e]^T) ----------
// N-tile = 64 a-rows + 64 b-rows interleaved per wave-col-half so SwiGLU pairs in-register
__global__ __launch_bounds__(256, 2) void g1_t(
    const float* __restrict__ x, const float* __restrict__ w_in,
    const int* __restrict__ ws_i, const int* __restrict__ e0,
    const int* __restrict__ e1, u16* __restrict__ act)
{
    const int nt = ws_i[99];
    if ((int)blockIdx.y >= nt) return;
    const int tile = ws_i[512 + blockIdx.y];
    const int e  = tile >> 16;
    const int rb = tile & 0xFFFF;        // global padded row base (mult 128)
    const int nc = blockIdx.x;           // 0..7 -> h-cols nc*64..+63

    __shared__ u16 xs[128][72];
    __shared__ u16 wt[128][72];
    __shared__ int tokL[128];

    const int tid = threadIdx.x;
    if (tid < 128) {
        const int ent = (rb >= NP1) ? e1[rb - NP1 + tid] : e0[rb + tid];
        tokL[tid] = (ent < 0) ? 0 : (ent >> 1);
    }
    __syncthreads();

    const int wid = tid >> 6, ln = tid & 63, qd = ln >> 4, lm = ln & 15;
    const int wrh = wid >> 1, wch = wid & 1;   // wave row-half / col-half
    const int srow = tid >> 4, sseg = tid & 15;

    int xtok[8], wrow[8];
    #pragma unroll
    for (int s = 0; s < 8; ++s) {
        const int R = s * 16 + srow;
        xtok[s] = tokL[R];
        const int h = R >> 6, r2 = R & 63;
        wrow[s] = (r2 < 32) ? (nc * 64 + h * 32 + r2)
                            : (512 + nc * 64 + h * 32 + (r2 - 32));
    }
    const float* wbase = w_in + ((size_t)e << 20);

    f32x4 acc[4][4];
    #pragma unroll
    for (int i = 0; i < 4; ++i)
        #pragma unroll
        for (int j = 0; j < 4; ++j) acc[i][j] = (f32x4){0.f,0.f,0.f,0.f};

    for (int k0 = 0; k0 < 1024; k0 += 64) {
        float4 xv[8], wv[8];
        #pragma unroll
        for (int s = 0; s < 8; ++s)
            xv[s] = *(const float4*)(x + ((size_t)xtok[s] << 10) + k0 + (sseg << 2));
        #pragma unroll
        for (int s = 0; s < 8; ++s)
            wv[s] = *(const float4*)(wbase + ((size_t)wrow[s] << 10) + k0 + (sseg << 2));
        __syncthreads();                          // prior frag reads done
        #pragma unroll
        for (int s = 0; s < 8; ++s) {
            uint2 p; p.x = pk2(xv[s].x, xv[s].y); p.y = pk2(xv[s].z, xv[s].w);
            *(uint2*)&xs[s * 16 + srow][sseg << 2] = p;
        }
        #pragma unroll
        for (int s = 0; s < 8; ++s) {
            uint2 p; p.x = pk2(wv[s].x, wv[s].y); p.y = pk2(wv[s].z, wv[s].w);
            *(uint2*)&wt[s * 16 + srow][sseg << 2] = p;
        }
        __syncthreads();
        #pragma unroll
        for (int ki = 0; ki < 2; ++ki) {
            const int ko = ki * 32 + (qd << 3);
            bf16x8 aF[4], bF[4];
            #pragma unroll
            for (int i = 0; i < 4; ++i) aF[i] = LDF(xs, wrh * 64 + i * 16 + lm, ko);
            #pragma unroll
            for (int j = 0; j < 4; ++j) bF[j] = LDF(wt, wch * 64 + j * 16 + lm, ko);
            #pragma unroll
            for (int i = 0; i < 4; ++i)
                #pragma unroll
                for (int j = 0; j < 4; ++j)
                    acc[i][j] = MFMA(aF[i], bF[j], acc[i][j]);
        }
    }

    // SwiGLU in-register: j (a) pairs with j+2 (b), same lane
    #pragma unroll
    for (int i = 0; i < 4; ++i) {
        #pragma unroll
        for (int j = 0; j < 2; ++j) {
            #pragma unroll
            for (int r = 0; r < 4; ++r) {
                const float a = acc[i][j][r], b = acc[i][j + 2][r];
                const float v = b * a / (1.f + __expf(-a));
                const int row  = wrh * 64 + i * 16 + (qd << 2) + r;
                const int hcol = nc * 64 + wch * 32 + j * 16 + lm;
                act[((size_t)(rb + row) << 9) + hcol] = f2bf(v);
            }
        }
    }
}

// ---------- g2: 128x128 tile, y = gate * (act @ w_out[e]^T) ----------
__global__ __launch_bounds__(256, 2) void g2_t(
    const u16* __restrict__ act, const float* __restrict__ w_out,
    const int* __restrict__ ws_i, const int* __restrict__ e0,
    const int* __restrict__ e1, const float* __restrict__ top_g,
    u16* __restrict__ y)
{
    const int nt = ws_i[99];
    if ((int)blockIdx.y >= nt) return;
    const int tile = ws_i[512 + blockIdx.y];
    const int e  = tile >> 16;
    const int rb = tile & 0xFFFF;
    const int dc = blockIdx.x;           // out cols dc*128..+127

    __shared__ u16   as_[128][72];
    __shared__ u16   wt2[128][72];
    __shared__ float gateL[128];

    const int tid = threadIdx.x;
    if (tid < 128) {
        const int ent = (rb >= NP1) ? e1[rb - NP1 + tid] : e0[rb + tid];
        gateL[tid] = (ent < 0) ? 0.f : top_g[ent];
    }
    __syncthreads();

    const int wid = tid >> 6, ln = tid & 63, qd = ln >> 4, lm = ln & 15;
    const int wrh = wid >> 1, wch = wid & 1;
    const int srow = tid >> 4, sseg = tid & 15;
    const int ar = tid >> 3, aseg = tid & 7;       // act staging: 32 rows/step, 8 uint4 cols

    const float* wbase = w_out + ((size_t)e << 19) + (((size_t)dc << 7) << 9);

    f32x4 acc[4][4];
    #pragma unroll
    for (int i = 0; i < 4; ++i)
        #pragma unroll
        for (int j = 0; j < 4; ++j) acc[i][j] = (f32x4){0.f,0.f,0.f,0.f};

    for (int k0 = 0; k0 < 512; k0 += 64) {
        uint4 av[4];
        float4 wv[8];
        #pragma unroll
        for (int s = 0; s < 4; ++s)
            av[s] = *(const uint4*)(act + ((size_t)(rb + s * 32 + ar) << 9) + k0 + (aseg << 3));
        #pragma unroll
        for (int s = 0; s < 8; ++s)
            wv[s] = *(const float4*)(wbase + ((size_t)(s * 16 + srow) << 9) + k0 + (sseg << 2));
        __syncthreads();
        #pragma unroll
        for (int s = 0; s < 4; ++s)
            *(uint4*)&as_[s * 32 + ar][aseg << 3] = av[s];
        #pragma unroll
        for (int s = 0; s < 8; ++s) {
            uint2 p; p.x = pk2(wv[s].x, wv[s].y); p.y = pk2(wv[s].z, wv[s].w);
            *(uint2*)&wt2[s * 16 + srow][sseg << 2] = p;
        }
        __syncthreads();
        #pragma unroll
        for (int ki = 0; ki < 2; ++ki) {
            const int ko = ki * 32 + (qd << 3);
            bf16x8 aF[4], bF[4];
            #pragma unroll
            for (int i = 0; i < 4; ++i) aF[i] = LDF(as_, wrh * 64 + i * 16 + lm, ko);
            #pragma unroll
            for (int j = 0; j < 4; ++j) bF[j] = LDF(wt2, wch * 64 + j * 16 + lm, ko);
            #pragma unroll
            for (int i = 0; i < 4; ++i)
                #pragma unroll
                for (int j = 0; j < 4; ++j)
                    acc[i][j] = MFMA(aF[i], bF[j], acc[i][j]);
        }
    }

    #pragma unroll
    for (int i = 0; i < 4; ++i) {
        #pragma unroll
        for (int j = 0; j < 4; ++j) {
            #pragma unroll
            for (int r = 0; r < 4; ++r) {
                const int row = wrh * 64 + i * 16 + (qd << 2) + r;
                const int col = (dc << 7) + wch * 64 + j * 16 + lm;
                y[((size_t)(rb + row) << 10) + col] = f2bf(gateL[row] * acc[i][j][r]);
            }
        }
    }
}

// ---------- combine: out[t] = y[pos0[t]] + y[NP1 + pos1[t]] ----------
__global__ __launch_bounds__(256) void combine_kernel(
    const u16* __restrict__ y, const int* __restrict__ posmap,
    float* __restrict__ out)
{
    const int idx = blockIdx.x * 256 + threadIdx.x;   // 524288 total
    const int t  = idx >> 7;
    const int c8 = (idx & 127) << 3;
    const int r0 = posmap[2 * t];
    const int r1 = NP1 + posmap[2 * t + 1];
    const uint4 a = *(const uint4*)(y + ((size_t)r0 << 10) + c8);
    const uint4 b = *(const uint4*)(y + ((size_t)r1 << 10) + c8);
    float4 o0, o1;
    o0.x = blo(a.x) + blo(b.x); o0.y = bhi(a.x) + bhi(b.x);
    o0.z = blo(a.y) + blo(b.y); o0.w = bhi(a.y) + bhi(b.y);
    o1.x = blo(a.z) + blo(b.z); o1.y = bhi(a.z) + bhi(b.z);
    o1.z = blo(a.w) + blo(b.w); o1.w = bhi(a.w) + bhi(b.w);
    float* po = out + ((size_t)t << 10) + c8;
    *(float4*)po       = o0;
    *(float4*)(po + 4) = o1;
}

extern "C" void kernel_launch(void* const* d_in, const int* in_sizes, int n_in,
                              void* d_out, int out_size, void* d_ws, size_t ws_size,
                              hipStream_t stream)
{
    (void)in_sizes; (void)n_in; (void)out_size; (void)ws_size;
    const float* x     = (const float*)d_in[0];   // [4096,1024] fp32
    const float* wr    = (const float*)d_in[1];   // [8,1024]
    const float* w_in  = (const float*)d_in[2];   // [8,1024,1024]
    const float* w_out = (const float*)d_in[3];   // [8,1024,512]
    float* out = (float*)d_out;                   // [4096*1024] out ++ [4096*8] logits

    char* ws = (char*)d_ws;                           // ~31.6 MB total
    int*   ws_i   = (int*)ws;                         //  4 KB control + tile table
    int*   e0     = (int*)(ws + 8192);                // 20 KB entries pass 0
    int*   e1     = (int*)(ws + 28672);               // 20 KB entries pass 1
    int*   top_e  = (int*)(ws + 49152);               // 32 KB
    float* top_g  = (float*)(ws + 81920);             // 32 KB
    int*   posmap = (int*)(ws + 114688);              // 32 KB
    u16*   act    = (u16*)(ws + 147456);              // 10240*512*2  = 10.5 MB
    u16*   y      = (u16*)(ws + 147456 + (size_t)10240 * 512 * 2);  // 10240*1024*2 = 21 MB

    router_kernel<<<256, 256, 0, stream>>>(x, wr, out + (size_t)T_TOK * D_DIM, top_e, top_g);
    prep_kernel<<<1, 256, 0, stream>>>(top_e, ws_i, e0, e1, posmap);
    g1_t<<<dim3(8, 80), 256, 0, stream>>>(x, w_in, ws_i, e0, e1, act);
    g2_t<<<dim3(8, 80), 256, 0, stream>>>(act, w_out, ws_i, e0, e1, top_g, y);
    combine_kernel<<<2048, 256, 0, stream>>>(y, posmap, out);
}

// Round 10
// 207.201 us; speedup vs baseline: 1.5724x; 1.1465x over previous
//
#include <hip/hip_runtime.h>

typedef unsigned short u16;
typedef unsigned int   u32;

#define T_TOK 4096
#define D_DIM 1024
#define H_DIM 512
#define E_NUM 8
#define NP1   5120        // padded rows per pass (buckets padded to 128)
#define MAXP  5120

typedef __bf16 bf16x8 __attribute__((ext_vector_type(8)));
typedef float  f32x4  __attribute__((ext_vector_type(4)));

__device__ __forceinline__ u16 f2bf(float f) {
    return __builtin_bit_cast(u16, (__bf16)f);
}
__device__ __forceinline__ u32 pk2(float a, float b) {
    return (u32)f2bf(a) | ((u32)f2bf(b) << 16);
}

// async 16B global->LDS; per-lane gaddr, wave-uniform LDS base (data lands at base+lane*16)
__device__ __forceinline__ void gll16(const void* g, void* l) {
    __builtin_amdgcn_global_load_lds((const __attribute__((address_space(1))) void*)g,
                                     (__attribute__((address_space(3))) void*)l, 16, 0, 0);
}

// frag read with XOR de-swizzle: tile [128][64] u16, slot = seg ^ (row&7)
#define LDFX(arr, r, ko) __builtin_bit_cast(bf16x8, \
    *(const uint4*)(&arr[r][((((ko) >> 3) ^ ((r) & 7)) << 3)]))
#define MFMA(a, b, c) __builtin_amdgcn_mfma_f32_16x16x32_bf16(a, b, c, 0, 0, 0)

// ---------- conv1: w_in fp32 -> bf16 ----------
__global__ __launch_bounds__(256) void conv1_kernel(
    const float* __restrict__ w_in, u16* __restrict__ wib)
{
    const int i = blockIdx.x * 256 + threadIdx.x;     // 1M threads, 8 els each
    const float4 a = *(const float4*)(w_in + (size_t)i * 8);
    const float4 b = *(const float4*)(w_in + (size_t)i * 8 + 4);
    uint4 o;
    o.x = pk2(a.x, a.y); o.y = pk2(a.z, a.w);
    o.z = pk2(b.x, b.y); o.w = pk2(b.z, b.w);
    *(uint4*)(wib + (size_t)i * 8) = o;
}

// ---------- conv2: w_out fp32 -> bf16 (runs after g1; overwrites dead xb) ----------
__global__ __launch_bounds__(256) void conv2_kernel(
    const float* __restrict__ w_out, u16* __restrict__ wob)
{
    const int i = blockIdx.x * 256 + threadIdx.x;     // 512K threads, 8 els each
    const float4 a = *(const float4*)(w_out + (size_t)i * 8);
    const float4 b = *(const float4*)(w_out + (size_t)i * 8 + 4);
    uint4 o;
    o.x = pk2(a.x, a.y); o.y = pk2(a.z, a.w);
    o.z = pk2(b.x, b.y); o.w = pk2(b.z, b.w);
    *(uint4*)(wob + (size_t)i * 8) = o;
}

// ---------- router: logits + top-2 gates + bf16 x emit; no atomics ----------
__global__ __launch_bounds__(256) void router_kernel(
    const float* __restrict__ x, const float* __restrict__ wr,
    float* __restrict__ logits_out, int* __restrict__ top_e, float* __restrict__ top_g,
    u16* __restrict__ xb)
{
    __shared__ float wrL[E_NUM][1024];
    const int tid = threadIdx.x;
    #pragma unroll
    for (int i = 0; i < 8; ++i) {
        const int idx = (i * 256 + tid) * 4;
        *(float4*)&wrL[0][idx] = *(const float4*)(wr + idx);
    }
    __syncthreads();

    const int lane = tid & 63;
    const int wv   = tid >> 6;
    const int t0   = blockIdx.x * 16 + wv * 4;

    for (int tt = 0; tt < 4; ++tt) {
        const int t = t0 + tt;
        const float* xr = x + ((size_t)t << 10);
        float4 xv[4];
        #pragma unroll
        for (int j = 0; j < 4; ++j)
            xv[j] = *(const float4*)(xr + j * 256 + lane * 4);

        #pragma unroll
        for (int j = 0; j < 4; ++j) {
            uint2 p;
            p.x = pk2(xv[j].x, xv[j].y);
            p.y = pk2(xv[j].z, xv[j].w);
            *(uint2*)(xb + ((size_t)t << 10) + j * 256 + lane * 4) = p;
        }

        float acc[E_NUM];
        #pragma unroll
        for (int e = 0; e < E_NUM; ++e) acc[e] = 0.f;
        #pragma unroll
        for (int j = 0; j < 4; ++j) {
            #pragma unroll
            for (int e = 0; e < E_NUM; ++e) {
                const float4 w4 = *(const float4*)&wrL[e][j * 256 + lane * 4];
                acc[e] += xv[j].x * w4.x + xv[j].y * w4.y + xv[j].z * w4.z + xv[j].w * w4.w;
            }
        }
        #pragma unroll
        for (int off = 32; off >= 1; off >>= 1) {
            #pragma unroll
            for (int e = 0; e < E_NUM; ++e)
                acc[e] += __shfl_xor(acc[e], off);
        }
        if (lane == 0) {
            #pragma unroll
            for (int e = 0; e < E_NUM; ++e)
                logits_out[t * E_NUM + e] = acc[e];
            int i0 = 0; float v0 = acc[0];
            #pragma unroll
            for (int e = 1; e < E_NUM; ++e) { if (acc[e] > v0) { v0 = acc[e]; i0 = e; } }
            int i1 = (i0 == 0) ? 1 : 0; float v1 = acc[i1];
            #pragma unroll
            for (int e = 0; e < E_NUM; ++e) { if (e != i0 && e != i1 && acc[e] > v1) { v1 = acc[e]; i1 = e; } }
            const float ed = __expf(v1 - v0);
            const float g0 = 1.f / (1.f + ed);
            top_e[2 * t]     = i0;  top_e[2 * t + 1] = i1;
            top_g[2 * t]     = g0;  top_g[2 * t + 1] = 1.f - g0;
        }
    }
}

// ---------- prep: histogram + offsets + expert-major tile tables + scatter ----------
// ws_i: [0..15] counts, [64..79] local offsets, [99] g1 ntiles, [100..101] g2 ntiles,
//       g1 tab @512 (<=80): (e<<16)|rb_global ; g2 tab0 @768, tab1 @896 (<=40 each): (e<<16)|rb_local
__global__ __launch_bounds__(256) void prep_kernel(
    const int* __restrict__ top_e, int* __restrict__ ws_i,
    int* __restrict__ e0, int* __restrict__ e1)
{
    __shared__ int hist[16];
    __shared__ int cur[16];
    const int tid = threadIdx.x;
    if (tid < 16) hist[tid] = 0;
    for (int i = tid; i < MAXP; i += 256) { e0[i] = -1; e1[i] = -1; }
    __syncthreads();
    for (int i = tid; i < 2 * T_TOK; i += 256)
        atomicAdd(&hist[2 * (top_e[i] & 7) + (i & 1)], 1);
    __syncthreads();
    if (tid == 0) {
        int off[16];
        int s0 = 0, s1 = 0;
        for (int e = 0; e < E_NUM; ++e) {
            off[2 * e]     = s0; s0 += (hist[2 * e]     + 127) & ~127;
            off[2 * e + 1] = s1; s1 += (hist[2 * e + 1] + 127) & ~127;
        }
        int nt1 = 0, nt20 = 0, nt21 = 0;
        for (int e = 0; e < E_NUM; ++e) {       // expert-major: both passes adjacent
            for (int k = 0; k < 2; ++k) {
                const int b  = 2 * e + k;
                const int pc = (hist[b] + 127) & ~127;
                ws_i[b]      = hist[b];
                ws_i[64 + b] = off[b];
                cur[b]       = off[b];
                for (int j = 0; j < pc / 128; ++j) {
                    const int rl = off[b] + j * 128;
                    if (nt1 < 96) ws_i[512 + nt1++] = (e << 16) | (k * NP1 + rl);
                    if (k == 0) { if (nt20 < 48) ws_i[768 + nt20++] = (e << 16) | rl; }
                    else        { if (nt21 < 48) ws_i[896 + nt21++] = (e << 16) | rl; }
                }
            }
        }
        ws_i[99]  = nt1;
        ws_i[100] = nt20;
        ws_i[101] = nt21;
    }
    __syncthreads();
    for (int i = tid; i < 2 * T_TOK; i += 256) {
        const int b   = 2 * (top_e[i] & 7) + (i & 1);
        const int pos = atomicAdd(&cur[b], 1);
        ((i & 1) ? e1 : e0)[pos] = i;
    }
}

// ---------- g1: 128x128 tile, async bf16 staging, act = swiglu(xb @ wib[e]^T) ----------
__global__ __launch_bounds__(256, 2) void g1_a(
    const u16* __restrict__ xb, const u16* __restrict__ wib,
    const int* __restrict__ ws_i, const int* __restrict__ e0,
    const int* __restrict__ e1, u16* __restrict__ act)
{
    const int nt = ws_i[99];
    if ((int)blockIdx.y >= nt) return;
    const int tile = ws_i[512 + blockIdx.y];
    const int e  = tile >> 16;
    const int rb = tile & 0xFFFF;        // global padded row base (mult 128)
    const int nc = blockIdx.x;           // h-col block 0..7

    __shared__ __align__(16) u16 xs[128][64];
    __shared__ __align__(16) u16 wt[128][64];
    __shared__ int tokL[128];

    const int tid = threadIdx.x;
    if (tid < 128) {
        const int ent = (rb >= NP1) ? e1[rb - NP1 + tid] : e0[rb + tid];
        tokL[tid] = (ent < 0) ? 0 : (ent >> 1);
    }
    __syncthreads();

    const int wid = tid >> 6, ln = tid & 63, qd = ln >> 4, lm = ln & 15;
    const int wrh = wid >> 1, wch = wid & 1;

    // per-lane gather setup: 4 xs rows + 4 wt rows (8 lanes/row, XOR-swizzled segs)
    const u16* xsrc[4];
    const u16* wsrc[4];
    const u16* wbase = wib + ((size_t)e << 20);
    #pragma unroll
    for (int j = 0; j < 4; ++j) {
        const int r  = wid * 32 + j * 8 + (ln >> 3);
        const int sg = (ln & 7) ^ (r & 7);
        xsrc[j] = xb + ((size_t)tokL[r] << 10) + (sg << 3);
        const int h = r >> 6, r2 = r & 63;
        const int wrow = (r2 < 32) ? (nc * 64 + h * 32 + r2)
                                   : (512 + nc * 64 + h * 32 + (r2 - 32));
        wsrc[j] = wbase + ((size_t)wrow << 10) + (sg << 3);
    }

    f32x4 acc[4][4];
    #pragma unroll
    for (int i = 0; i < 4; ++i)
        #pragma unroll
        for (int j = 0; j < 4; ++j) acc[i][j] = (f32x4){0.f,0.f,0.f,0.f};

    for (int k0 = 0; k0 < 1024; k0 += 64) {
        #pragma unroll
        for (int j = 0; j < 4; ++j) {
            gll16(xsrc[j] + k0, &xs[wid * 32 + j * 8][0]);
            gll16(wsrc[j] + k0, &wt[wid * 32 + j * 8][0]);
        }
        __syncthreads();                          // drains vmcnt; tiles ready
        #pragma unroll
        for (int ki = 0; ki < 2; ++ki) {
            const int ko = ki * 32 + (qd << 3);
            bf16x8 aF[4], bF[4];
            #pragma unroll
            for (int i = 0; i < 4; ++i) aF[i] = LDFX(xs, wrh * 64 + i * 16 + lm, ko);
            #pragma unroll
            for (int j = 0; j < 4; ++j) bF[j] = LDFX(wt, wch * 64 + j * 16 + lm, ko);
            #pragma unroll
            for (int i = 0; i < 4; ++i)
                #pragma unroll
                for (int j = 0; j < 4; ++j)
                    acc[i][j] = MFMA(aF[i], bF[j], acc[i][j]);
        }
        __syncthreads();                          // frag reads done before overwrite
    }

    // SwiGLU in-register: j (a-half) pairs with j+2 (b-half), same lane
    #pragma unroll
    for (int i = 0; i < 4; ++i) {
        #pragma unroll
        for (int j = 0; j < 2; ++j) {
            #pragma unroll
            for (int r = 0; r < 4; ++r) {
                const float a = acc[i][j][r], b = acc[i][j + 2][r];
                const float v = b * a / (1.f + __expf(-a));
                const int row  = wrh * 64 + i * 16 + (qd << 2) + r;
                const int hcol = nc * 64 + wch * 32 + j * 16 + lm;
                act[((size_t)(rb + row) << 9) + hcol] = f2bf(v);
            }
        }
    }
}

// ---------- g2: 128x128 tile, async bf16 staging, out (+)= gate*(act @ wob[e]^T) ----------
// pass 0: plain store (k=0 rows cover each token once); pass 1: RMW (stream-ordered)
__global__ __launch_bounds__(256, 2) void g2_a(
    const u16* __restrict__ act, const u16* __restrict__ wob,
    const int* __restrict__ ws_i, const int* __restrict__ entries,
    const float* __restrict__ top_g, float* __restrict__ out, int pass)
{
    const int nt = ws_i[100 + pass];
    if ((int)blockIdx.y >= nt) return;
    const int tile = ws_i[(pass ? 896 : 768) + blockIdx.y];
    const int e   = tile >> 16;
    const int rbl = tile & 0xFFFF;       // local padded row base
    const int dc  = blockIdx.x;          // out-col block 0..7
    const int ab  = pass * NP1 + rbl;    // act global row base

    __shared__ __align__(16) u16 as_[128][64];
    __shared__ __align__(16) u16 wt2[128][64];
    __shared__ int   entL[128];
    __shared__ float gateL[128];

    const int tid = threadIdx.x;
    if (tid < 128) {
        const int ent = entries[rbl + tid];
        entL[tid]  = ent;
        gateL[tid] = (ent < 0) ? 0.f : top_g[ent];
    }
    __syncthreads();

    const int wid = tid >> 6, ln = tid & 63, qd = ln >> 4, lm = ln & 15;
    const int wrh = wid >> 1, wch = wid & 1;

    const u16* asrc[4];
    const u16* wsrc[4];
    const u16* wbase = wob + ((size_t)e << 19);
    #pragma unroll
    for (int j = 0; j < 4; ++j) {
        const int r  = wid * 32 + j * 8 + (ln >> 3);
        const int sg = (ln & 7) ^ (r & 7);
        asrc[j] = act + ((size_t)(ab + r) << 9) + (sg << 3);
        wsrc[j] = wbase + ((size_t)((dc << 7) + r) << 9) + (sg << 3);
    }

    f32x4 acc[4][4];
    #pragma unroll
    for (int i = 0; i < 4; ++i)
        #pragma unroll
        for (int j = 0; j < 4; ++j) acc[i][j] = (f32x4){0.f,0.f,0.f,0.f};

    for (int k0 = 0; k0 < 512; k0 += 64) {
        #pragma unroll
        for (int j = 0; j < 4; ++j) {
            gll16(asrc[j] + k0, &as_[wid * 32 + j * 8][0]);
            gll16(wsrc[j] + k0, &wt2[wid * 32 + j * 8][0]);
        }
        __syncthreads();
        #pragma unroll
        for (int ki = 0; ki < 2; ++ki) {
            const int ko = ki * 32 + (qd << 3);
            bf16x8 aF[4], bF[4];
            #pragma unroll
            for (int i = 0; i < 4; ++i) aF[i] = LDFX(as_, wrh * 64 + i * 16 + lm, ko);
            #pragma unroll
            for (int j = 0; j < 4; ++j) bF[j] = LDFX(wt2, wch * 64 + j * 16 + lm, ko);
            #pragma unroll
            for (int i = 0; i < 4; ++i)
                #pragma unroll
                for (int j = 0; j < 4; ++j)
                    acc[i][j] = MFMA(aF[i], bF[j], acc[i][j]);
        }
        __syncthreads();
    }

    #pragma unroll
    for (int i = 0; i < 4; ++i) {
        #pragma unroll
        for (int j = 0; j < 4; ++j) {
            #pragma unroll
            for (int r = 0; r < 4; ++r) {
                const int row = wrh * 64 + i * 16 + (qd << 2) + r;
                const int ent = entL[row];
                if (ent >= 0) {
                    const int t   = ent >> 1;
                    const int col = (dc << 7) + wch * 64 + j * 16 + lm;
                    float* po = out + ((size_t)t << 10) + col;
                    float v = gateL[row] * acc[i][j][r];
                    if (pass) v += *po;
                    *po = v;
                }
            }
        }
    }
}

extern "C" void kernel_launch(void* const* d_in, const int* in_sizes, int n_in,
                              void* d_out, int out_size, void* d_ws, size_t ws_size,
                              hipStream_t stream)
{
    (void)in_sizes; (void)n_in; (void)out_size; (void)ws_size;
    const float* x     = (const float*)d_in[0];   // [4096,1024] fp32
    const float* wr    = (const float*)d_in[1];   // [8,1024]
    const float* w_in  = (const float*)d_in[2];   // [8,1024,1024]
    const float* w_out = (const float*)d_in[3];   // [8,1024,512]
    float* out = (float*)d_out;                   // [4096*1024] out ++ [4096*8] logits

    char* ws = (char*)d_ws;                           // peak 34.1 MB (<= 43 MB proven)
    int*   ws_i  = (int*)ws;                          //  8 KB control + tables
    int*   e0    = (int*)(ws + 8192);                 // 20 KB entries pass 0
    int*   e1    = (int*)(ws + 28672);                // 20 KB entries pass 1
    int*   top_e = (int*)(ws + 49152);                // 32 KB
    float* top_g = (float*)(ws + 81920);              // 32 KB
    u16*   act   = (u16*)(ws + 147456);               // 10240*512*2 = 10.5 MB
    u16*   xb    = (u16*)(ws + 10633216);             //  8 MB bf16 x
    u16*   wob   = (u16*)(ws + 10633216);             //  8 MB bf16 w_out (over dead xb)
    u16*   wib   = (u16*)(ws + 19021824);             // 16 MB bf16 w_in

    conv1_kernel<<<4096, 256, 0, stream>>>(w_in, wib);
    router_kernel<<<256, 256, 0, stream>>>(x, wr, out + (size_t)T_TOK * D_DIM,
                                           top_e, top_g, xb);
    prep_kernel<<<1, 256, 0, stream>>>(top_e, ws_i, e0, e1);
    g1_a<<<dim3(8, 80), 256, 0, stream>>>(xb, wib, ws_i, e0, e1, act);
    conv2_kernel<<<2048, 256, 0, stream>>>(w_out, wob);
    g2_a<<<dim3(8, 40), 256, 0, stream>>>(act, wob, ws_i, e0, top_g, out, 0);
    g2_a<<<dim3(8, 40), 256, 0, stream>>>(act, wob, ws_i, e1, top_g, out, 1);
}